// Round 5
// baseline (174.560 us; speedup 1.0000x reference)
//
#include <hip/hip_runtime.h>
#include <hip/hip_cooperative_groups.h>

namespace cg = cooperative_groups;

typedef __attribute__((ext_vector_type(8))) short short8;
typedef __attribute__((ext_vector_type(4))) float f32x4;

#define TANH_SCALE 2.8853900817779268f  /* 2*log2(e): exp(2x) = exp2(x*TANH_SCALE) */
#define LOG_EPS   -18.420680743952367f  /* log(1e-8f): exact masked-out additive */

static __device__ __forceinline__ unsigned short f2bf(float f) {
  unsigned u = __builtin_bit_cast(unsigned, f);
  u += 0x7FFFu + ((u >> 16) & 1u);   // round-to-nearest-even
  return (unsigned short)(u >> 16);
}
static __device__ __forceinline__ float bf2f(unsigned short h) {
  unsigned u = (unsigned)h << 16;
  return __builtin_bit_cast(float, u);
}

// ONE cooperative kernel, 256 blocks x 1024 threads (1 block/CU, 16 waves/CU).
// Phase 1: fp32->bf16 convert (grid-stride).           grid.sync()
// Phase 2: both projection GEMMs + exp2 epilogue.      grid.sync()
// Phase 3: fused scores + masked log-softmax.
__global__ __launch_bounds__(1024) void ptr_attn_all(
    const float4* __restrict__ dec, const float4* __restrict__ enc,
    const float* __restrict__ mask,
    const float4* __restrict__ W1, const float4* __restrict__ W2,
    const float* __restrict__ vt,
    unsigned short* __restrict__ dec_b, unsigned short* __restrict__ enc_b,
    unsigned short* __restrict__ w1_b, unsigned short* __restrict__ w2_b,
    float* __restrict__ decPt, unsigned short* __restrict__ encPb,
    float* __restrict__ out) {
  cg::grid_group grid = cg::this_grid();
  const int tid = threadIdx.x;

  // ---------------- Phase 1: conversions ----------------
  // float4 regions: dec 131072 | enc 262144 (->393216) | W1 32768 (->425984) | W2 32768 (->458752)
  {
    int idx = blockIdx.x * 1024 + tid;
    for (int j = idx; j < 458752; j += 262144) {
      const float4* src; ushort4* dst; int off;
      if (j < 131072)            { src = dec; dst = (ushort4*)dec_b; off = 0; }
      else if (j < 393216)       { src = enc; dst = (ushort4*)enc_b; off = 131072; }
      else if (j < 425984)       { src = W1;  dst = (ushort4*)w1_b;  off = 393216; }
      else                       { src = W2;  dst = (ushort4*)w2_b;  off = 425984; }
      int k = j - off;
      float4 v = src[k];
      ushort4 o;
      o.x = f2bf(v.x); o.y = f2bf(v.y); o.z = f2bf(v.z); o.w = f2bf(v.w);
      dst[k] = o;
    }
  }
  grid.sync();

  // ---------------- Phase 2: projection GEMMs ----------------
  // 768 sub-blocks of 256 threads (4 waves), 16x16 wave tile, K=512.
  //   sub in [0,256):   decPt(256x1024) fp32 = exp2(c * W1 . dec^T); mt=sub>>6, nt=sub&63
  //   sub in [256,768): encPb(8,256,256) bf16 = exp2(c * W2 . enc^T); z, mt, nt per batch
  // Mapping sub = q*256 + blockIdx -> every block has exactly 3 active quarters.
  {
    const int q = tid >> 8;
    const int sub = q * 256 + blockIdx.x;
    if (sub < 768) {
      const int K = 512;
      const unsigned short *A, *Bp;
      int N, mt, nt;
      bool is_dec = (sub < 256);
      size_t cbase = 0;
      if (is_dec) {
        A = w1_b; Bp = dec_b; N = 1024;
        mt = sub >> 6; nt = sub & 63;
      } else {
        int e = sub - 256, z = e >> 6, rem = e & 63;
        A = w2_b; Bp = enc_b + (size_t)z * 256 * K; N = 256;
        mt = rem >> 4; nt = rem & 15;
        cbase = (size_t)z * 256 * 256;
      }
      const int st = tid & 255;               // thread id within sub-block
      const int wave = st >> 6, lane = st & 63;
      const int m0 = mt * 64 + wave * 16;
      const int n0 = nt * 16;
      const int l16 = lane & 15, quad = lane >> 4, kb = quad * 8;

      f32x4 acc = {0.f, 0.f, 0.f, 0.f};
      const unsigned short* ap = A + (long)(m0 + l16) * K + kb;
      const unsigned short* bp = Bp + (long)(n0 + l16) * K + kb;
#pragma unroll 4
      for (int ks = 0; ks < K; ks += 32) {
        short8 a = *(const short8*)(ap + ks);
        short8 b = *(const short8*)(bp + ks);
        acc = __builtin_amdgcn_mfma_f32_16x16x32_bf16(a, b, acc, 0, 0, 0);
      }
      // C/D layout: col = lane&15, row = quad*4 + reg
      int n = n0 + l16;
      if (is_dec) {
#pragma unroll
        for (int r = 0; r < 4; ++r) {
          int m = m0 + quad * 4 + r;
          decPt[(long)m * N + n] = __builtin_amdgcn_exp2f(acc[r] * TANH_SCALE);
        }
      } else {
#pragma unroll
        for (int r = 0; r < 4; ++r) {
          int m = m0 + quad * 4 + r;
          encPb[cbase + (long)m * N + n] =
              f2bf(__builtin_amdgcn_exp2f(acc[r] * TANH_SCALE));
        }
      }
    }
  }
  grid.sync();

  // ---------------- Phase 3: fused scores + masked log-softmax ----------------
  // scores = -2 * sum_l vt[l] * rcp(P[t][l]*E[s][l] + 1) (+ softmax-invariant const, dropped)
  {
    const int T = 128, S = 256, L = 256;
    const int b = blockIdx.x >> 5;
    const int t0 = (blockIdx.x & 31) * 4;
    const int s = tid & 255;
    const int q = tid >> 8;
    const int l0 = q * (L / 4);

    const unsigned short* __restrict__ ep = encPb + (size_t)b * L * S + (size_t)l0 * S + s;
    const float* __restrict__ dp = decPt + (size_t)(b * T + t0) + (size_t)l0 * 1024;

    float acc0 = 0.f, acc1 = 0.f, acc2 = 0.f, acc3 = 0.f;
#pragma unroll 8
    for (int l = 0; l < L / 4; ++l) {
      float e = bf2f(ep[(size_t)l * S]);
      float4 P = *(const float4*)(dp + (size_t)l * 1024);  // wave-uniform -> s_load
      float v = vt[l0 + l];
      float r0 = __builtin_amdgcn_rcpf(fmaf(P.x, e, 1.0f));
      float r1 = __builtin_amdgcn_rcpf(fmaf(P.y, e, 1.0f));
      float r2 = __builtin_amdgcn_rcpf(fmaf(P.z, e, 1.0f));
      float r3 = __builtin_amdgcn_rcpf(fmaf(P.w, e, 1.0f));
      acc0 = fmaf(v, r0, acc0);
      acc1 = fmaf(v, r1, acc1);
      acc2 = fmaf(v, r2, acc2);
      acc3 = fmaf(v, r3, acc3);
    }

    __shared__ float partial[4][4][256];   // [quarter][t][s]
    partial[q][0][s] = acc0;
    partial[q][1][s] = acc1;
    partial[q][2][s] = acc2;
    partial[q][3][s] = acc3;
    __syncthreads();

    float lg = partial[0][q][s] + partial[1][q][s] + partial[2][q][s] + partial[3][q][s];

    // mask is exactly 0.0 or 1.0 and 1.0f+1e-8f == 1.0f in fp32, so
    // log(mask+eps) == (mask != 0 ? 0 : log(1e-8f)) exactly.
    const float LN2 = 0.6931471805599453f, L2E = 1.4426950408889634f;
    {
      float m = mask[(size_t)(b * T + t0 + q) * S + s];
      lg = fmaf(-2.0f, lg, (m != 0.0f) ? 0.0f : LOG_EPS);
    }

    __shared__ float redm[16], reds[16];
    const int wid = tid >> 6, lane = tid & 63;

    float w = lg;
#pragma unroll
    for (int off = 1; off < 64; off <<= 1) w = fmaxf(w, __shfl_xor(w, off));
    if (lane == 0) redm[wid] = w;
    __syncthreads();
    float bm = fmaxf(fmaxf(redm[q * 4 + 0], redm[q * 4 + 1]),
                     fmaxf(redm[q * 4 + 2], redm[q * 4 + 3]));

    float e = __builtin_amdgcn_exp2f((lg - bm) * L2E);
#pragma unroll
    for (int off = 1; off < 64; off <<= 1) e += __shfl_xor(e, off);
    if (lane == 0) reds[wid] = e;
    __syncthreads();
    float sum = reds[q * 4 + 0] + reds[q * 4 + 1] + reds[q * 4 + 2] + reds[q * 4 + 3];

    out[(size_t)(b * T + t0 + q) * S + s] = lg - bm - LN2 * __builtin_amdgcn_logf(sum);
  }
}

extern "C" void kernel_launch(void* const* d_in, const int* in_sizes, int n_in,
                              void* d_out, int out_size, void* d_ws, size_t ws_size,
                              hipStream_t stream) {
  const float* dec = (const float*)d_in[0];   // (8,128,512)
  const float* enc = (const float*)d_in[1];   // (8,256,512)
  const float* mask = (const float*)d_in[2];  // (8,128,256)
  const float* W1 = (const float*)d_in[3];    // (256,512)
  const float* W2 = (const float*)d_in[4];    // (256,512)
  const float* vt = (const float*)d_in[5];    // (256)
  float* out = (float*)d_out;                 // (8,128,256)

  char* ws = (char*)d_ws;
  unsigned short* dec_b = (unsigned short*)(ws);                     // 1 MB
  unsigned short* enc_b = (unsigned short*)(ws + (1u << 20));        // 2 MB
  unsigned short* w1_b  = (unsigned short*)(ws + 3u * (1u << 20));   // 256 KB
  unsigned short* w2_b  = (unsigned short*)(ws + 3u * (1u << 20) + (256u << 10));
  float* decPt = (float*)(ws + 3u * (1u << 20) + (512u << 10));      // 1 MB (L x BT) fp32
  unsigned short* encPb = (unsigned short*)(ws + 4u * (1u << 20) + (512u << 10)); // 1 MB bf16

  void* args[] = {
      (void*)&dec, (void*)&enc, (void*)&mask, (void*)&W1, (void*)&W2, (void*)&vt,
      (void*)&dec_b, (void*)&enc_b, (void*)&w1_b, (void*)&w2_b,
      (void*)&decPt, (void*)&encPb, (void*)&out};
  hipLaunchCooperativeKernel((const void*)ptr_attn_all, dim3(256), dim3(1024),
                             args, 0, stream);
  (void)in_sizes; (void)n_in; (void)out_size; (void)ws_size;
}

// Round 6
// 106.364 us; speedup vs baseline: 1.6412x; 1.6412x over previous
//
#include <hip/hip_runtime.h>

typedef __attribute__((ext_vector_type(8))) short short8;
typedef __attribute__((ext_vector_type(4))) float f32x4;

#define TANH_SCALE 2.8853900817779268f  /* 2*log2(e): exp(2x) = exp2(x*TANH_SCALE) */
#define LOG_EPS   -18.420680743952367f  /* log(1e-8f): exact masked-out additive */

static __device__ __forceinline__ unsigned short f2bf(float f) {
  unsigned u = __builtin_bit_cast(unsigned, f);
  u += 0x7FFFu + ((u >> 16) & 1u);   // round-to-nearest-even
  return (unsigned short)(u >> 16);
}
static __device__ __forceinline__ float bf2f(unsigned short h) {
  unsigned u = (unsigned)h << 16;
  return __builtin_bit_cast(float, u);
}
static __device__ __forceinline__ short8 cvt8(float4 lo, float4 hi) {
  short8 r;
  r[0] = (short)f2bf(lo.x); r[1] = (short)f2bf(lo.y);
  r[2] = (short)f2bf(lo.z); r[3] = (short)f2bf(lo.w);
  r[4] = (short)f2bf(hi.x); r[5] = (short)f2bf(hi.y);
  r[6] = (short)f2bf(hi.z); r[7] = (short)f2bf(hi.w);
  return r;
}

// Combined NT GEMM for both projections with INLINE fp32->bf16 conversion and
// exp2(TANH_SCALE*x) epilogue. Wave tile 16x32 (2 MFMA/k-step); 384 blocks x 4 waves.
//   blocks [0,128):   decPt(256x1024) fp32 = exp2(c * W1 . dec^T)
//   blocks [128,384): encPb(8,256,256) bf16 = exp2(c * W2 . enc^T) per batch
// All inputs fp32; conversion to bf16 (RNE) happens in registers right before MFMA,
// numerically identical to a separate pre-convert pass.
__global__ __launch_bounds__(256) void gemm_proj_cvt(
    const float* __restrict__ W1, const float* __restrict__ W2,
    const float* __restrict__ dec, const float* __restrict__ enc,
    float* __restrict__ decPt, unsigned short* __restrict__ encPb) {
  const int K = 512;
  int idx = blockIdx.x;
  const float *A, *Bp;
  int N, mt, nt;
  bool is_dec = (idx < 128);
  size_t cbase = 0;
  if (is_dec) {
    A = W1; Bp = dec; N = 1024;
    mt = idx >> 5; nt = idx & 31;
  } else {
    int j = idx - 128, z = j >> 5, rem = j & 31;
    A = W2; Bp = enc + (size_t)z * 256 * K; N = 256;
    mt = rem >> 3; nt = rem & 7;
    cbase = (size_t)z * 256 * 256;
  }
  const int tid = threadIdx.x, wave = tid >> 6, lane = tid & 63;
  const int m0 = mt * 64 + wave * 16;
  const int n0 = nt * 32;
  const int l16 = lane & 15, quad = lane >> 4, kb = quad * 8;

  f32x4 acc0 = {0.f,0.f,0.f,0.f}, acc1 = {0.f,0.f,0.f,0.f};

  const float* ap  = A + (long)(m0 + l16) * K + kb;
  const float* bp0 = Bp + (long)(n0 + l16) * K + kb;
  const float* bp1 = bp0 + 16 * K;

  for (int ks = 0; ks < K; ks += 32) {
    float4 aL = *(const float4*)(ap + ks),  aH = *(const float4*)(ap + ks + 4);
    float4 b0L = *(const float4*)(bp0 + ks), b0H = *(const float4*)(bp0 + ks + 4);
    float4 b1L = *(const float4*)(bp1 + ks), b1H = *(const float4*)(bp1 + ks + 4);
    short8 a  = cvt8(aL, aH);
    short8 b0 = cvt8(b0L, b0H);
    short8 b1 = cvt8(b1L, b1H);
    acc0 = __builtin_amdgcn_mfma_f32_16x16x32_bf16(a, b0, acc0, 0, 0, 0);
    acc1 = __builtin_amdgcn_mfma_f32_16x16x32_bf16(a, b1, acc1, 0, 0, 0);
  }

  // C/D layout: col = lane&15, row = quad*4 + reg. Store exp2(c*acc), coalesced in n.
  f32x4 accs[2] = {acc0, acc1};
  if (is_dec) {
#pragma unroll
    for (int j = 0; j < 2; ++j) {
      int n = n0 + j * 16 + l16;
#pragma unroll
      for (int r = 0; r < 4; ++r) {
        int m = m0 + quad * 4 + r;
        decPt[(long)m * N + n] = __builtin_amdgcn_exp2f(accs[j][r] * TANH_SCALE);
      }
    }
  } else {
#pragma unroll
    for (int j = 0; j < 2; ++j) {
      int n = n0 + j * 16 + l16;
#pragma unroll
      for (int r = 0; r < 4; ++r) {
        int m = m0 + quad * 4 + r;
        encPb[cbase + (long)m * N + n] =
            f2bf(__builtin_amdgcn_exp2f(accs[j][r] * TANH_SCALE));
      }
    }
  }
}

// Fused scores + masked log-softmax.
//   scores = -2 * sum_l vt[l] * rcp(P[t][l]*E[s][l] + 1)  (+ softmax-invariant const, dropped)
// decPt: (L=256, BT=1024) fp32 transposed exp2-form; encPb: (B,L,S) bf16 exp2-form.
// Block = 1024 threads: s = tid&255, quarter q = tid>>8 does l in [64q, 64q+64).
// Block covers 4 consecutive t; epilogue: quarter q owns softmax of row t0+q.
// Grid = B*T/4 = 256 blocks x 16 waves -> 4 waves/SIMD, 1 block/CU.
__global__ __launch_bounds__(1024) void fused_score_softmax(
    const float* __restrict__ decPt, const unsigned short* __restrict__ encPb,
    const float* __restrict__ mask, const float* __restrict__ vt,
    float* __restrict__ out) {
  const int T = 128, S = 256, L = 256;
  const int b = blockIdx.x >> 5;
  const int t0 = (blockIdx.x & 31) * 4;
  const int s = threadIdx.x & 255;
  const int q = threadIdx.x >> 8;
  const int l0 = q * (L / 4);

  const unsigned short* __restrict__ ep = encPb + (size_t)b * L * S + (size_t)l0 * S + s;
  const float* __restrict__ dp = decPt + (size_t)(b * T + t0) + (size_t)l0 * 1024;

  float acc0 = 0.f, acc1 = 0.f, acc2 = 0.f, acc3 = 0.f;
#pragma unroll 8
  for (int l = 0; l < L / 4; ++l) {
    float e = bf2f(ep[(size_t)l * S]);
    float4 P = *(const float4*)(dp + (size_t)l * 1024);   // wave-uniform -> s_load
    float v = vt[l0 + l];
    float r0 = __builtin_amdgcn_rcpf(fmaf(P.x, e, 1.0f));
    float r1 = __builtin_amdgcn_rcpf(fmaf(P.y, e, 1.0f));
    float r2 = __builtin_amdgcn_rcpf(fmaf(P.z, e, 1.0f));
    float r3 = __builtin_amdgcn_rcpf(fmaf(P.w, e, 1.0f));
    acc0 = fmaf(v, r0, acc0);
    acc1 = fmaf(v, r1, acc1);
    acc2 = fmaf(v, r2, acc2);
    acc3 = fmaf(v, r3, acc3);
  }

  // combine l-quarters: everyone writes, then quarter q owns row t0+q
  __shared__ float partial[4][4][256];   // [quarter][t][s]
  partial[q][0][s] = acc0;
  partial[q][1][s] = acc1;
  partial[q][2][s] = acc2;
  partial[q][3][s] = acc3;
  __syncthreads();

  float lg = partial[0][q][s] + partial[1][q][s] + partial[2][q][s] + partial[3][q][s];

  // mask is exactly 0.0 or 1.0, and 1.0f + 1e-8f == 1.0f in fp32, so
  // log(mask+eps) == (mask != 0 ? 0 : log(1e-8f)) exactly.
  const float LN2 = 0.6931471805599453f, L2E = 1.4426950408889634f;
  {
    float m = mask[(size_t)(b * T + t0 + q) * S + s];
    lg = fmaf(-2.0f, lg, (m != 0.0f) ? 0.0f : LOG_EPS);
  }

  // softmax over s (256 wide = the 4 waves of this quarter)
  __shared__ float redm[16], reds[16];
  const int wid = threadIdx.x >> 6, lane = threadIdx.x & 63;

  float w = lg;
#pragma unroll
  for (int off = 1; off < 64; off <<= 1) w = fmaxf(w, __shfl_xor(w, off));
  if (lane == 0) redm[wid] = w;
  __syncthreads();
  float bm = fmaxf(fmaxf(redm[q * 4 + 0], redm[q * 4 + 1]),
                   fmaxf(redm[q * 4 + 2], redm[q * 4 + 3]));

  float e = __builtin_amdgcn_exp2f((lg - bm) * L2E);
#pragma unroll
  for (int off = 1; off < 64; off <<= 1) e += __shfl_xor(e, off);
  if (lane == 0) reds[wid] = e;
  __syncthreads();
  float sum = reds[q * 4 + 0] + reds[q * 4 + 1] + reds[q * 4 + 2] + reds[q * 4 + 3];

  out[(size_t)(b * T + t0 + q) * S + s] = lg - bm - LN2 * __builtin_amdgcn_logf(sum);
}

extern "C" void kernel_launch(void* const* d_in, const int* in_sizes, int n_in,
                              void* d_out, int out_size, void* d_ws, size_t ws_size,
                              hipStream_t stream) {
  const int B = 8, T = 128;
  const float* dec = (const float*)d_in[0];   // (8,128,512)
  const float* enc = (const float*)d_in[1];   // (8,256,512)
  const float* mask = (const float*)d_in[2];  // (8,128,256)
  const float* W1 = (const float*)d_in[3];    // (256,512)
  const float* W2 = (const float*)d_in[4];    // (256,512)
  const float* vt = (const float*)d_in[5];    // (256)
  float* out = (float*)d_out;                 // (8,128,256)

  char* ws = (char*)d_ws;
  float* decPt = (float*)(ws);                              // 1 MB (L x BT) fp32
  unsigned short* encPb = (unsigned short*)(ws + (1u << 20)); // 1 MB (B,L,S) bf16

  // 1) both projections, inline fp32->bf16, exp2 epilogue (384 blocks, 1536 waves)
  gemm_proj_cvt<<<384, 256, 0, stream>>>(W1, W2, dec, enc, decPt, encPb);

  // 2) fused scores + masked log-softmax (256 blocks x 1024 threads, 4096 waves)
  fused_score_softmax<<<B * T / 4, 1024, 0, stream>>>(decPt, encPb, mask, vt, out);
  (void)in_sizes; (void)n_in; (void)out_size; (void)ws_size;
}

// Round 7
// 95.862 us; speedup vs baseline: 1.8210x; 1.1096x over previous
//
#include <hip/hip_runtime.h>

typedef __attribute__((ext_vector_type(8))) short short8;
typedef __attribute__((ext_vector_type(4))) float f32x4;

#define TANH_SCALE 2.8853900817779268f  /* 2*log2(e): exp(2x) = exp2(x*TANH_SCALE) */
#define LOG_EPS   -18.420680743952367f  /* log(1e-8f): exact masked-out additive */

static __device__ __forceinline__ unsigned short f2bf(float f) {
  unsigned u = __builtin_bit_cast(unsigned, f);
  u += 0x7FFFu + ((u >> 16) & 1u);   // round-to-nearest-even
  return (unsigned short)(u >> 16);
}
static __device__ __forceinline__ float bf2f(unsigned short h) {
  unsigned u = (unsigned)h << 16;
  return __builtin_bit_cast(float, u);
}

// One launch converts all four fp32 tensors to bf16 (region-decoded by flat index).
// Region sizes in float4 units: dec 131072 | enc 262144 | W1 32768 | W2 32768.
__global__ __launch_bounds__(256) void cvt_all(
    const float4* __restrict__ dec, const float4* __restrict__ enc,
    const float4* __restrict__ W1, const float4* __restrict__ W2,
    ushort4* __restrict__ dec_b, ushort4* __restrict__ enc_b,
    ushort4* __restrict__ w1_b, ushort4* __restrict__ w2_b) {
  int i = blockIdx.x * 256 + threadIdx.x;
  const float4* src; ushort4* dst; int off;
  if (i < 131072)            { src = dec; dst = dec_b; off = 0; }
  else if (i < 131072+262144){ src = enc; dst = enc_b; off = 131072; }
  else if (i < 131072+262144+32768) { src = W1; dst = w1_b; off = 131072+262144; }
  else                       { src = W2; dst = w2_b; off = 131072+262144+32768; }
  int j = i - off;
  float4 v = src[j];
  ushort4 o;
  o.x = f2bf(v.x); o.y = f2bf(v.y); o.z = f2bf(v.z); o.w = f2bf(v.w);
  dst[j] = o;
}

// Combined NT GEMM for both projections with exp2(TANH_SCALE*x) epilogue.
// Wave tile 16x32 (2 MFMA/k-step): 1536 waves (~1.5/SIMD). K-loop FULLY unrolled
// (16 iters) so the compiler hoists independent global loads deep ahead of the
// MFMAs — the kernel is latency-bound at this occupancy.
//   blocks [0,128):   decPt(256x1024) fp32 = exp2(c * W1 . dec^T)
//   blocks [128,384): encPb(8,256,256) bf16 = exp2(c * W2 . enc^T) per batch
__global__ __launch_bounds__(256) void gemm_proj(
    const unsigned short* __restrict__ w1b, const unsigned short* __restrict__ w2b,
    const unsigned short* __restrict__ decb, const unsigned short* __restrict__ encb,
    float* __restrict__ decPt, unsigned short* __restrict__ encPb) {
  const int K = 512;
  int idx = blockIdx.x;
  const unsigned short *A, *Bp;
  int N, mt, nt;
  bool is_dec = (idx < 128);
  size_t cbase = 0;
  if (is_dec) {
    A = w1b; Bp = decb; N = 1024;
    mt = idx >> 5; nt = idx & 31;
  } else {
    int j = idx - 128, z = j >> 5, rem = j & 31;
    A = w2b; Bp = encb + (size_t)z * 256 * K; N = 256;
    mt = rem >> 3; nt = rem & 7;
    cbase = (size_t)z * 256 * 256;
  }
  const int tid = threadIdx.x, wave = tid >> 6, lane = tid & 63;
  const int m0 = mt * 64 + wave * 16;
  const int n0 = nt * 32;
  const int l16 = lane & 15, quad = lane >> 4, kb = quad * 8;

  f32x4 acc0 = {0.f,0.f,0.f,0.f}, acc1 = {0.f,0.f,0.f,0.f};

  const unsigned short* ap  = A + (long)(m0 + l16) * K + kb;
  const unsigned short* bp0 = Bp + (long)(n0 + l16) * K + kb;

#pragma unroll
  for (int ks = 0; ks < K; ks += 32) {
    short8 a  = *(const short8*)(ap + ks);
    short8 b0 = *(const short8*)(bp0 + ks);
    short8 b1 = *(const short8*)(bp0 + 16 * K + ks);
    acc0 = __builtin_amdgcn_mfma_f32_16x16x32_bf16(a, b0, acc0, 0, 0, 0);
    acc1 = __builtin_amdgcn_mfma_f32_16x16x32_bf16(a, b1, acc1, 0, 0, 0);
  }

  // C/D layout: col = lane&15, row = quad*4 + reg. Store exp2(c*acc), coalesced in n.
  f32x4 accs[2] = {acc0, acc1};
  if (is_dec) {
#pragma unroll
    for (int j = 0; j < 2; ++j) {
      int n = n0 + j * 16 + l16;
#pragma unroll
      for (int r = 0; r < 4; ++r) {
        int m = m0 + quad * 4 + r;
        decPt[(long)m * N + n] = __builtin_amdgcn_exp2f(accs[j][r] * TANH_SCALE);
      }
    }
  } else {
#pragma unroll
    for (int j = 0; j < 2; ++j) {
      int n = n0 + j * 16 + l16;
#pragma unroll
      for (int r = 0; r < 4; ++r) {
        int m = m0 + quad * 4 + r;
        encPb[cbase + (long)m * N + n] =
            f2bf(__builtin_amdgcn_exp2f(accs[j][r] * TANH_SCALE));
      }
    }
  }
}

// Fused scores + masked log-softmax.
//   scores = -2 * sum_l vt[l] * rcp(P[t][l]*E[s][l] + 1)  (+ softmax-invariant const, dropped)
// decPt: (L=256, BT=1024) fp32 transposed exp2-form; encPb: (B,L,S) bf16 exp2-form.
// Block = 1024 threads: s = tid&255, quarter q = tid>>8 does l in [64q, 64q+64).
// Block covers 4 consecutive t; epilogue: quarter q owns softmax of row t0+q.
// Grid = B*T/4 = 256 blocks x 16 waves -> 4 waves/SIMD, 1 block/CU.
__global__ __launch_bounds__(1024) void fused_score_softmax(
    const float* __restrict__ decPt, const unsigned short* __restrict__ encPb,
    const float* __restrict__ mask, const float* __restrict__ vt,
    float* __restrict__ out) {
  const int T = 128, S = 256, L = 256;
  const int b = blockIdx.x >> 5;
  const int t0 = (blockIdx.x & 31) * 4;
  const int s = threadIdx.x & 255;
  const int q = threadIdx.x >> 8;
  const int l0 = q * (L / 4);

  const unsigned short* __restrict__ ep = encPb + (size_t)b * L * S + (size_t)l0 * S + s;
  const float* __restrict__ dp = decPt + (size_t)(b * T + t0) + (size_t)l0 * 1024;

  float acc0 = 0.f, acc1 = 0.f, acc2 = 0.f, acc3 = 0.f;
#pragma unroll 8
  for (int l = 0; l < L / 4; ++l) {
    float e = bf2f(ep[(size_t)l * S]);
    float4 P = *(const float4*)(dp + (size_t)l * 1024);   // wave-uniform -> s_load
    float v = vt[l0 + l];
    float r0 = __builtin_amdgcn_rcpf(fmaf(P.x, e, 1.0f));
    float r1 = __builtin_amdgcn_rcpf(fmaf(P.y, e, 1.0f));
    float r2 = __builtin_amdgcn_rcpf(fmaf(P.z, e, 1.0f));
    float r3 = __builtin_amdgcn_rcpf(fmaf(P.w, e, 1.0f));
    acc0 = fmaf(v, r0, acc0);
    acc1 = fmaf(v, r1, acc1);
    acc2 = fmaf(v, r2, acc2);
    acc3 = fmaf(v, r3, acc3);
  }

  // combine l-quarters: everyone writes, then quarter q owns row t0+q
  __shared__ float partial[4][4][256];   // [quarter][t][s]
  partial[q][0][s] = acc0;
  partial[q][1][s] = acc1;
  partial[q][2][s] = acc2;
  partial[q][3][s] = acc3;
  __syncthreads();

  float lg = partial[0][q][s] + partial[1][q][s] + partial[2][q][s] + partial[3][q][s];

  // mask is exactly 0.0 or 1.0, and 1.0f + 1e-8f == 1.0f in fp32, so
  // log(mask+eps) == (mask != 0 ? 0 : log(1e-8f)) exactly.
  const float LN2 = 0.6931471805599453f, L2E = 1.4426950408889634f;
  {
    float m = mask[(size_t)(b * T + t0 + q) * S + s];
    lg = fmaf(-2.0f, lg, (m != 0.0f) ? 0.0f : LOG_EPS);
  }

  // softmax over s (256 wide = the 4 waves of this quarter)
  __shared__ float redm[16], reds[16];
  const int wid = threadIdx.x >> 6, lane = threadIdx.x & 63;

  float w = lg;
#pragma unroll
  for (int off = 1; off < 64; off <<= 1) w = fmaxf(w, __shfl_xor(w, off));
  if (lane == 0) redm[wid] = w;
  __syncthreads();
  float bm = fmaxf(fmaxf(redm[q * 4 + 0], redm[q * 4 + 1]),
                   fmaxf(redm[q * 4 + 2], redm[q * 4 + 3]));

  float e = __builtin_amdgcn_exp2f((lg - bm) * L2E);
#pragma unroll
  for (int off = 1; off < 64; off <<= 1) e += __shfl_xor(e, off);
  if (lane == 0) reds[wid] = e;
  __syncthreads();
  float sum = reds[q * 4 + 0] + reds[q * 4 + 1] + reds[q * 4 + 2] + reds[q * 4 + 3];

  out[(size_t)(b * T + t0 + q) * S + s] = lg - bm - LN2 * __builtin_amdgcn_logf(sum);
}

extern "C" void kernel_launch(void* const* d_in, const int* in_sizes, int n_in,
                              void* d_out, int out_size, void* d_ws, size_t ws_size,
                              hipStream_t stream) {
  const int B = 8, T = 128;
  const float* dec = (const float*)d_in[0];   // (8,128,512)
  const float* enc = (const float*)d_in[1];   // (8,256,512)
  const float* mask = (const float*)d_in[2];  // (8,128,256)
  const float* W1 = (const float*)d_in[3];    // (256,512)
  const float* W2 = (const float*)d_in[4];    // (256,512)
  const float* vt = (const float*)d_in[5];    // (256)
  float* out = (float*)d_out;                 // (8,128,256)

  char* ws = (char*)d_ws;
  unsigned short* dec_b = (unsigned short*)(ws);                     // 1 MB
  unsigned short* enc_b = (unsigned short*)(ws + (1u << 20));        // 2 MB
  unsigned short* w1_b  = (unsigned short*)(ws + 3u * (1u << 20));   // 256 KB
  unsigned short* w2_b  = (unsigned short*)(ws + 3u * (1u << 20) + (256u << 10));
  float* decPt = (float*)(ws + 3u * (1u << 20) + (512u << 10));      // 1 MB (L x BT) fp32
  unsigned short* encPb = (unsigned short*)(ws + 4u * (1u << 20) + (512u << 10)); // 1 MB bf16

  // 1) all fp32->bf16 conversions in one launch
  cvt_all<<<1792, 256, 0, stream>>>(
      (const float4*)dec, (const float4*)enc, (const float4*)W1, (const float4*)W2,
      (ushort4*)dec_b, (ushort4*)enc_b, (ushort4*)w1_b, (ushort4*)w2_b);

  // 2) both projections + exp2 epilogue (384 blocks, 1536 waves)
  gemm_proj<<<384, 256, 0, stream>>>(w1_b, w2_b, dec_b, enc_b, decPt, encPb);

  // 3) fused scores + masked log-softmax (256 blocks x 1024 threads, 4096 waves)
  fused_score_softmax<<<B * T / 4, 1024, 0, stream>>>(decPt, encPb, mask, vt, out);
  (void)in_sizes; (void)n_in; (void)out_size; (void)ws_size;
}

// Round 8
// 90.902 us; speedup vs baseline: 1.9203x; 1.0546x over previous
//
#include <hip/hip_runtime.h>

typedef __attribute__((ext_vector_type(8))) short short8;
typedef __attribute__((ext_vector_type(4))) float f32x4;

#define TANH_SCALE 2.8853900817779268f  /* 2*log2(e): exp(2x) = exp2(x*TANH_SCALE) */
#define LOG_EPS   -18.420680743952367f  /* log(1e-8f): exact masked-out additive */
#define KC 128                           /* K-chunk staged through LDS */
#define LDP (KC + 8)                     /* LDS row stride (shorts): 16B-aligned rows,
                                            68 dwords -> uniform-optimal b128 banking */

static __device__ __forceinline__ unsigned short f2bf(float f) {
  unsigned u = __builtin_bit_cast(unsigned, f);
  u += 0x7FFFu + ((u >> 16) & 1u);   // round-to-nearest-even
  return (unsigned short)(u >> 16);
}
static __device__ __forceinline__ float bf2f(unsigned short h) {
  unsigned u = (unsigned)h << 16;
  return __builtin_bit_cast(float, u);
}

// Merged fp32->bf16 conversion + NT GEMM for both projections, exp2 epilogue.
// Per K-chunk: global fp32 -> registers -> (RNE cvt) -> LDS bf16 -> MFMA.
// Conversion happens ONCE per tile-touch at staging time (off the MFMA dependency
// path) — unlike the R6 inline-cvt which re-converted per use inside the K-loop.
// Register prefetch of chunk c+1 issues during chunk c's MFMAs (loads stay in
// flight across the first barrier).
//   blocks [0,128):   decPt(256x1024) fp32 = exp2(c * W1 . dec^T)
//   blocks [128,384): encPb(8,256,256) bf16 = exp2(c * W2 . enc^T) per batch
// Block = 4 waves, block tile 64(M)x32(N); wave w: rows [64mt+16w,+16) x 32 cols.
__global__ __launch_bounds__(256) void gemm_proj_cvt(
    const float* __restrict__ W1, const float* __restrict__ W2,
    const float* __restrict__ dec, const float* __restrict__ enc,
    float* __restrict__ decPt, unsigned short* __restrict__ encPb) {
  const int K = 512;
  int idx = blockIdx.x;
  const float *A, *Bp;
  int N, mt, nt;
  bool is_dec = (idx < 128);
  size_t cbase = 0;
  if (is_dec) {
    A = W1; Bp = dec; N = 1024;
    mt = idx >> 5; nt = idx & 31;
  } else {
    int j = idx - 128, z = j >> 5, rem = j & 31;
    A = W2; Bp = enc + (size_t)z * 256 * K; N = 256;
    mt = rem >> 3; nt = rem & 7;
    cbase = (size_t)z * 65536;
  }
  const int tid = threadIdx.x, wave = tid >> 6, lane = tid & 63;
  const int m0 = mt * 64;            // block-level A row base
  const int n0 = nt * 32;            // block-level B row base
  const int l16 = lane & 15, quad = lane >> 4, kb = quad * 8;

  __shared__ unsigned short lA[64][LDP];   // 17408 B
  __shared__ unsigned short lB[32][LDP];   //  8704 B

  f32x4 acc0 = {0.f,0.f,0.f,0.f}, acc1 = {0.f,0.f,0.f,0.f};

  // Staging: thread covers 8 A-float4 + 4 B-float4 per chunk.
  // f = i*256 + tid -> row = f>>5, c4 = f&31  (KC/4 = 32 float4 per row)
  float4 ra[8], rb[4];
#pragma unroll
  for (int i = 0; i < 8; ++i) {
    int f = i * 256 + tid, row = f >> 5, c4 = f & 31;
    ra[i] = *(const float4*)(A + (size_t)(m0 + row) * K + c4 * 4);
  }
#pragma unroll
  for (int i = 0; i < 4; ++i) {
    int f = i * 256 + tid, row = f >> 5, c4 = f & 31;
    rb[i] = *(const float4*)(Bp + (size_t)(n0 + row) * K + c4 * 4);
  }

#pragma unroll
  for (int kc = 0; kc < 4; ++kc) {
    // convert + write staged chunk to LDS
#pragma unroll
    for (int i = 0; i < 8; ++i) {
      int f = i * 256 + tid, row = f >> 5, c4 = f & 31;
      ushort4 o = { f2bf(ra[i].x), f2bf(ra[i].y), f2bf(ra[i].z), f2bf(ra[i].w) };
      *(ushort4*)&lA[row][c4 * 4] = o;
    }
#pragma unroll
    for (int i = 0; i < 4; ++i) {
      int f = i * 256 + tid, row = f >> 5, c4 = f & 31;
      ushort4 o = { f2bf(rb[i].x), f2bf(rb[i].y), f2bf(rb[i].z), f2bf(rb[i].w) };
      *(ushort4*)&lB[row][c4 * 4] = o;
    }
    __syncthreads();
    // prefetch next chunk (loads overlap the MFMAs below)
    if (kc < 3) {
      int k0n = (kc + 1) * KC;
#pragma unroll
      for (int i = 0; i < 8; ++i) {
        int f = i * 256 + tid, row = f >> 5, c4 = f & 31;
        ra[i] = *(const float4*)(A + (size_t)(m0 + row) * K + k0n + c4 * 4);
      }
#pragma unroll
      for (int i = 0; i < 4; ++i) {
        int f = i * 256 + tid, row = f >> 5, c4 = f & 31;
        rb[i] = *(const float4*)(Bp + (size_t)(n0 + row) * K + k0n + c4 * 4);
      }
    }
    // MFMA from LDS
#pragma unroll
    for (int ks = 0; ks < KC; ks += 32) {
      short8 a  = *(const short8*)&lA[wave * 16 + l16][ks + kb];
      short8 b0 = *(const short8*)&lB[l16][ks + kb];
      short8 b1 = *(const short8*)&lB[16 + l16][ks + kb];
      acc0 = __builtin_amdgcn_mfma_f32_16x16x32_bf16(a, b0, acc0, 0, 0, 0);
      acc1 = __builtin_amdgcn_mfma_f32_16x16x32_bf16(a, b1, acc1, 0, 0, 0);
    }
    __syncthreads();
  }

  // C/D layout: col = lane&15, row = quad*4 + reg. Store exp2(c*acc), coalesced in n.
  f32x4 accs[2] = {acc0, acc1};
  if (is_dec) {
#pragma unroll
    for (int j = 0; j < 2; ++j) {
      int n = n0 + j * 16 + l16;
#pragma unroll
      for (int r = 0; r < 4; ++r) {
        int m = m0 + wave * 16 + quad * 4 + r;
        decPt[(long)m * N + n] = __builtin_amdgcn_exp2f(accs[j][r] * TANH_SCALE);
      }
    }
  } else {
#pragma unroll
    for (int j = 0; j < 2; ++j) {
      int n = n0 + j * 16 + l16;
#pragma unroll
      for (int r = 0; r < 4; ++r) {
        int m = m0 + wave * 16 + quad * 4 + r;
        encPb[cbase + (long)m * N + n] =
            f2bf(__builtin_amdgcn_exp2f(accs[j][r] * TANH_SCALE));
      }
    }
  }
}

// Fused scores + masked log-softmax (unchanged from R7).
//   scores = -2 * sum_l vt[l] * rcp(P[t][l]*E[s][l] + 1)  (+ softmax-invariant const, dropped)
// decPt: (L=256, BT=1024) fp32 transposed exp2-form; encPb: (B,L,S) bf16 exp2-form.
// Block = 1024 threads: s = tid&255, quarter q = tid>>8 does l in [64q, 64q+64).
// Block covers 4 consecutive t; epilogue: quarter q owns softmax of row t0+q.
// Grid = B*T/4 = 256 blocks x 16 waves -> 4 waves/SIMD, 1 block/CU.
__global__ __launch_bounds__(1024) void fused_score_softmax(
    const float* __restrict__ decPt, const unsigned short* __restrict__ encPb,
    const float* __restrict__ mask, const float* __restrict__ vt,
    float* __restrict__ out) {
  const int T = 128, S = 256, L = 256;
  const int b = blockIdx.x >> 5;
  const int t0 = (blockIdx.x & 31) * 4;
  const int s = threadIdx.x & 255;
  const int q = threadIdx.x >> 8;
  const int l0 = q * (L / 4);

  const unsigned short* __restrict__ ep = encPb + (size_t)b * L * S + (size_t)l0 * S + s;
  const float* __restrict__ dp = decPt + (size_t)(b * T + t0) + (size_t)l0 * 1024;

  float acc0 = 0.f, acc1 = 0.f, acc2 = 0.f, acc3 = 0.f;
#pragma unroll 8
  for (int l = 0; l < L / 4; ++l) {
    float e = bf2f(ep[(size_t)l * S]);
    float4 P = *(const float4*)(dp + (size_t)l * 1024);   // wave-uniform -> s_load
    float v = vt[l0 + l];
    float r0 = __builtin_amdgcn_rcpf(fmaf(P.x, e, 1.0f));
    float r1 = __builtin_amdgcn_rcpf(fmaf(P.y, e, 1.0f));
    float r2 = __builtin_amdgcn_rcpf(fmaf(P.z, e, 1.0f));
    float r3 = __builtin_amdgcn_rcpf(fmaf(P.w, e, 1.0f));
    acc0 = fmaf(v, r0, acc0);
    acc1 = fmaf(v, r1, acc1);
    acc2 = fmaf(v, r2, acc2);
    acc3 = fmaf(v, r3, acc3);
  }

  // combine l-quarters: everyone writes, then quarter q owns row t0+q
  __shared__ float partial[4][4][256];   // [quarter][t][s]
  partial[q][0][s] = acc0;
  partial[q][1][s] = acc1;
  partial[q][2][s] = acc2;
  partial[q][3][s] = acc3;
  __syncthreads();

  float lg = partial[0][q][s] + partial[1][q][s] + partial[2][q][s] + partial[3][q][s];

  // mask is exactly 0.0 or 1.0, and 1.0f + 1e-8f == 1.0f in fp32, so
  // log(mask+eps) == (mask != 0 ? 0 : log(1e-8f)) exactly.
  const float LN2 = 0.6931471805599453f, L2E = 1.4426950408889634f;
  {
    float m = mask[(size_t)(b * T + t0 + q) * S + s];
    lg = fmaf(-2.0f, lg, (m != 0.0f) ? 0.0f : LOG_EPS);
  }

  // softmax over s (256 wide = the 4 waves of this quarter)
  __shared__ float redm[16], reds[16];
  const int wid = threadIdx.x >> 6, lane = threadIdx.x & 63;

  float w = lg;
#pragma unroll
  for (int off = 1; off < 64; off <<= 1) w = fmaxf(w, __shfl_xor(w, off));
  if (lane == 0) redm[wid] = w;
  __syncthreads();
  float bm = fmaxf(fmaxf(redm[q * 4 + 0], redm[q * 4 + 1]),
                   fmaxf(redm[q * 4 + 2], redm[q * 4 + 3]));

  float e = __builtin_amdgcn_exp2f((lg - bm) * L2E);
#pragma unroll
  for (int off = 1; off < 64; off <<= 1) e += __shfl_xor(e, off);
  if (lane == 0) reds[wid] = e;
  __syncthreads();
  float sum = reds[q * 4 + 0] + reds[q * 4 + 1] + reds[q * 4 + 2] + reds[q * 4 + 3];

  out[(size_t)(b * T + t0 + q) * S + s] = lg - bm - LN2 * __builtin_amdgcn_logf(sum);
}

extern "C" void kernel_launch(void* const* d_in, const int* in_sizes, int n_in,
                              void* d_out, int out_size, void* d_ws, size_t ws_size,
                              hipStream_t stream) {
  const int B = 8, T = 128;
  const float* dec = (const float*)d_in[0];   // (8,128,512)
  const float* enc = (const float*)d_in[1];   // (8,256,512)
  const float* mask = (const float*)d_in[2];  // (8,128,256)
  const float* W1 = (const float*)d_in[3];    // (256,512)
  const float* W2 = (const float*)d_in[4];    // (256,512)
  const float* vt = (const float*)d_in[5];    // (256)
  float* out = (float*)d_out;                 // (8,128,256)

  char* ws = (char*)d_ws;
  float* decPt = (float*)(ws);                                // 1 MB (L x BT) fp32
  unsigned short* encPb = (unsigned short*)(ws + (1u << 20)); // 1 MB (B,L,S) bf16

  // 1) merged convert + both projections + exp2 epilogue (384 blocks, 1536 waves)
  gemm_proj_cvt<<<384, 256, 0, stream>>>(W1, W2, dec, enc, decPt, encPb);

  // 2) fused scores + masked log-softmax (256 blocks x 1024 threads, 4096 waves)
  fused_score_softmax<<<B * T / 4, 1024, 0, stream>>>(decPt, encPb, mask, vt, out);
  (void)in_sizes; (void)n_in; (void)out_size; (void)ws_size;
}